// Round 7
// baseline (1245.155 us; speedup 1.0000x reference)
//
#include <hip/hip_runtime.h>

// GCN 3-layer + JK-concat.  N=100000, E=1600000, F_IN=128, H=64, F_OUT=64.
//
// R6: dense kernels j-split. R2 measurement (751us): k_linfused 153us with
// VGPR=60 (acc[64] SPILLED) and Occupancy 17% (grid = exactly 1563 waves =
// 1.5/SIMD) -> latency-bound; VALUBusy*dur ~= 29us ~= FMA floor, so issue
// count is already minimal. Fix: each wave now does 64 rows x 32 cols
// (acc[32], no spill) -> 2x waves (3126, ~3/SIMD), plus double-buffered xb
// loads for intra-wave ILP. W stays on the scalar path (verified: SGPR=112).
//
// Algebra: h_next[d] = relu( dis[d] * ( u[d] + sum_{s->d} u[s] ) + b ),
//          u = (h @ W) * dis[row],  dis = rsqrt(1 + indeg)

#define N_NODES 100000
#define N_EDGES 1600000
#define F_IN    128
#define HID     64
#define NB_SCAN 98          // ceil(N_NODES / 1024)

// ================= CSR build =================
__global__ void k_zero(int* __restrict__ p, int n) {
    int i = blockIdx.x * blockDim.x + threadIdx.x;
    if (i < n) p[i] = 0;
}

__global__ void k_hist(const int* __restrict__ dst, int* __restrict__ counts) {
    int stride = gridDim.x * blockDim.x;
    for (int e = blockIdx.x * blockDim.x + threadIdx.x; e < N_EDGES; e += stride)
        atomicAdd(&counts[dst[e]], 1);
}

__global__ void k_blocksum(const int* __restrict__ counts, int* __restrict__ blksum) {
    __shared__ int red[256];
    int b = blockIdx.x, t = threadIdx.x;
    int base = b * 1024 + t * 4;
    int s = 0;
    #pragma unroll
    for (int q = 0; q < 4; q++) { int idx = base + q; if (idx < N_NODES) s += counts[idx]; }
    red[t] = s; __syncthreads();
    for (int off = 128; off > 0; off >>= 1) {
        if (t < off) red[t] += red[t + off];
        __syncthreads();
    }
    if (t == 0) blksum[b] = red[0];
}

__global__ void k_scan_top(int* __restrict__ blksum) {   // 1 block, 128 threads
    __shared__ int s[128];
    int t = threadIdx.x;
    s[t] = (t < NB_SCAN) ? blksum[t] : 0;
    __syncthreads();
    for (int off = 1; off < 128; off <<= 1) {
        int v = (t >= off) ? s[t - off] : 0;
        __syncthreads();
        s[t] += v;
        __syncthreads();
    }
    if (t < NB_SCAN) blksum[t] = (t == 0) ? 0 : s[t - 1];   // exclusive
}

__global__ void k_scan_write(const int* __restrict__ counts, const int* __restrict__ blkoff,
                             int* __restrict__ rowptr, int* __restrict__ cursor) {
    __shared__ int ts[256];
    int b = blockIdx.x, t = threadIdx.x;
    int base = b * 1024 + t * 4;
    int c[4]; int s = 0;
    #pragma unroll
    for (int q = 0; q < 4; q++) { int idx = base + q; c[q] = (idx < N_NODES) ? counts[idx] : 0; s += c[q]; }
    ts[t] = s; __syncthreads();
    for (int off = 1; off < 256; off <<= 1) {
        int v = (t >= off) ? ts[t - off] : 0;
        __syncthreads();
        ts[t] += v;
        __syncthreads();
    }
    int run = blkoff[b] + ((t == 0) ? 0 : ts[t - 1]);
    #pragma unroll
    for (int q = 0; q < 4; q++) {
        int idx = base + q;
        if (idx < N_NODES) { rowptr[idx] = run; cursor[idx] = run; run += c[q]; }
    }
}

__global__ void k_dis_from_counts(const int* __restrict__ counts, float* __restrict__ dis,
                                  int* __restrict__ rowptr) {
    int i = blockIdx.x * blockDim.x + threadIdx.x;
    if (i < N_NODES) dis[i] = rsqrtf(1.0f + (float)counts[i]);
    if (i == 0) rowptr[N_NODES] = N_EDGES;
}

__global__ void k_place(const int* __restrict__ src, const int* __restrict__ dst,
                        int* __restrict__ cursor, int* __restrict__ esorted) {
    int stride = gridDim.x * blockDim.x;
    for (int e = blockIdx.x * blockDim.x + threadIdx.x; e < N_EDGES; e += stride) {
        int d = dst[e];
        int pos = atomicAdd(&cursor[d], 1);
        esorted[pos] = src[e];
    }
}

// ================= dense: lane = row, 32-col half per wave =================
// acc[j] += X[row][k] * W[k][jbase+j], j in [0,32), k in [0,K).
// W has row stride 64; Wh = W + jbase. xb double-buffered for load/FMA overlap.
template<int K>
__device__ __forceinline__ void seg_accum32(const float* __restrict__ xr,
                                            const float* __restrict__ Wh,
                                            float (&acc)[32]) {
    float4 buf[4];
    #pragma unroll
    for (int q = 0; q < 4; q++)
        buf[q] = *reinterpret_cast<const float4*>(xr + 4 * q);
    #pragma unroll 1
    for (int k0 = 0; k0 < K; k0 += 16) {
        float xb[16];
        #pragma unroll
        for (int q = 0; q < 4; q++) {
            xb[4 * q + 0] = buf[q].x; xb[4 * q + 1] = buf[q].y;
            xb[4 * q + 2] = buf[q].z; xb[4 * q + 3] = buf[q].w;
        }
        if (k0 + 16 < K) {               // issue next tile's loads before FMAs
            #pragma unroll
            for (int q = 0; q < 4; q++)
                buf[q] = *reinterpret_cast<const float4*>(xr + k0 + 16 + 4 * q);
        }
        #pragma unroll
        for (int kk = 0; kk < 16; kk++) {
            const float* wk = Wh + (size_t)(k0 + kk) * 64;   // wave-uniform -> s_load
            #pragma unroll
            for (int j = 0; j < 32; j++)
                acc[j] = fmaf(xb[kk], wk[j], acc[j]);
        }
    }
}

// u[r][jh*32:(jh+1)*32] = (X[r][:] @ W[:, jh-half]) * dis[r]
template<int K>
__global__ __launch_bounds__(256, 4) void k_rowgemm(
        const float* __restrict__ X, const float* __restrict__ W,
        const float* __restrict__ dis, float* __restrict__ u) {
    const int lane   = threadIdx.x & 63;
    const int wid    = blockIdx.x * (blockDim.x >> 6) + (threadIdx.x >> 6);
    const int nwaves = gridDim.x * (blockDim.x >> 6);
    const int ntasks = ((N_NODES + 63) / 64) * 2;   // tile x col-half
    for (int task = wid; task < ntasks; task += nwaves) {
        const int tile = task >> 1, jh = task & 1;
        int r  = tile * 64 + lane;
        int rc = r < N_NODES ? r : N_NODES - 1;
        const float* xr = X + (size_t)rc * K;
        float acc[32];
        #pragma unroll
        for (int j = 0; j < 32; j++) acc[j] = 0.f;
        seg_accum32<K>(xr, W + jh * 32, acc);
        if (r < N_NODES) {
            float dv = dis[r];
            float* orow = u + (size_t)r * 64 + jh * 32;
            #pragma unroll
            for (int j4 = 0; j4 < 8; j4++) {
                float4 st = { acc[4*j4] * dv, acc[4*j4+1] * dv,
                              acc[4*j4+2] * dv, acc[4*j4+3] * dv };
                *reinterpret_cast<float4*>(orow + 4 * j4) = st;
            }
        }
    }
}

// out[r][half] = bl[half] + x[r]@Wl[0:128,half] + h1@Wl[128:192,half]
//              + h2@Wl[192:256,half] + h3@Wl[256:320,half]
__global__ __launch_bounds__(256, 4) void k_linfused(
        const float* __restrict__ x,  const float* __restrict__ h1,
        const float* __restrict__ h2, const float* __restrict__ h3,
        const float* __restrict__ Wl, const float* __restrict__ bl,
        float* __restrict__ out) {
    const int lane   = threadIdx.x & 63;
    const int wid    = blockIdx.x * (blockDim.x >> 6) + (threadIdx.x >> 6);
    const int nwaves = gridDim.x * (blockDim.x >> 6);
    const int ntasks = ((N_NODES + 63) / 64) * 2;
    for (int task = wid; task < ntasks; task += nwaves) {
        const int tile = task >> 1, jh = task & 1;
        int r  = tile * 64 + lane;
        int rc = r < N_NODES ? r : N_NODES - 1;
        float acc[32];
        const float* blh = bl + jh * 32;
        #pragma unroll
        for (int j = 0; j < 32; j++) acc[j] = blh[j];    // uniform -> s_load
        seg_accum32<F_IN>(x  + (size_t)rc * F_IN, Wl            + jh * 32, acc);
        seg_accum32<HID >(h1 + (size_t)rc * HID,  Wl + 128 * 64 + jh * 32, acc);
        seg_accum32<HID >(h2 + (size_t)rc * HID,  Wl + 192 * 64 + jh * 32, acc);
        seg_accum32<HID >(h3 + (size_t)rc * HID,  Wl + 256 * 64 + jh * 32, acc);
        if (r < N_NODES) {
            float* orow = out + (size_t)r * 64 + jh * 32;
            #pragma unroll
            for (int j4 = 0; j4 < 8; j4++) {
                float4 st = { acc[4*j4], acc[4*j4+1], acc[4*j4+2], acc[4*j4+3] };
                *reinterpret_cast<float4*>(orow + 4 * j4) = st;
            }
        }
    }
}

// ================= gather: h = relu(dis[d]*(u[d]+sum u[s]) + b) =================
__global__ __launch_bounds__(256) void k_gather_relu(
        const int* __restrict__ rowptr, const int* __restrict__ es,
        const float* __restrict__ u, const float* __restrict__ dis,
        const float* __restrict__ bias, float* __restrict__ hout) {
    const int lane = threadIdx.x & 63, wid = threadIdx.x >> 6, wpb = blockDim.x >> 6;
    const float bj = bias[lane];
    for (int d = blockIdx.x * wpb + wid; d < N_NODES; d += gridDim.x * wpb) {
        float a = u[(size_t)d * HID + lane];          // self loop
        int i = rowptr[d], end = rowptr[d + 1];
        for (; i + 4 <= end; i += 4) {
            int s0 = es[i], s1 = es[i + 1], s2 = es[i + 2], s3 = es[i + 3];
            float v0 = u[(size_t)s0 * HID + lane];
            float v1 = u[(size_t)s1 * HID + lane];
            float v2 = u[(size_t)s2 * HID + lane];
            float v3 = u[(size_t)s3 * HID + lane];
            a += v0; a += v1; a += v2; a += v3;
        }
        for (; i < end; i++) a += u[(size_t)es[i] * HID + lane];
        float v = fmaf(a, dis[d], bj);
        hout[(size_t)d * HID + lane] = v > 0.f ? v : 0.f;
    }
}

// ================= launch =================
extern "C" void kernel_launch(void* const* d_in, const int* in_sizes, int n_in,
                              void* d_out, int out_size, void* d_ws, size_t ws_size,
                              hipStream_t stream) {
    const float* x  = (const float*)d_in[0];
    const int*   ei = (const int*)d_in[1];      // edge_index [2, E] int32
    const float* W0 = (const float*)d_in[2];
    const float* b0 = (const float*)d_in[3];
    const float* W1 = (const float*)d_in[4];
    const float* b1 = (const float*)d_in[5];
    const float* W2 = (const float*)d_in[6];
    const float* b2 = (const float*)d_in[7];
    const float* Wl = (const float*)d_in[8];
    const float* bl = (const float*)d_in[9];
    float* out = (float*)d_out;

    const int* esrc = ei;
    const int* edst = ei + N_EDGES;

    // workspace layout (byte offsets; total ~110.5 MB)
    char* w = (char*)d_ws;
    float* dis     = (float*)(w);                       //   409,600 B
    float* u       = (float*)(w + 409600);              // 25,600,000
    float* h1      = (float*)(w + 26009600);            // 25,600,000
    float* h2      = (float*)(w + 51609600);            // 25,600,000
    float* h3      = (float*)(w + 77209600);            // 25,600,000
    int*   counts  = (int*)  (w + 102809600);           //    409,600
    int*   rowptr  = (int*)  (w + 103219200);           //    409,600 (N+1)
    int*   cursor  = (int*)  (w + 103628800);           //    409,600
    int*   esorted = (int*)  (w + 104038400);           //  6,400,000
    int*   blksum  = (int*)  (w + 110438400);           //        512

    const int nblk_nodes = (N_NODES + 255) / 256;
    const int GB = 782;   // ceil(1563 tiles * 2 col-halves / 4 waves-per-block)

    // CSR build (ws re-poisoned each call, so rebuild every time)
    k_zero<<<nblk_nodes, 256, 0, stream>>>(counts, N_NODES);
    k_hist<<<2048, 256, 0, stream>>>(edst, counts);
    k_blocksum<<<NB_SCAN, 256, 0, stream>>>(counts, blksum);
    k_scan_top<<<1, 128, 0, stream>>>(blksum);
    k_scan_write<<<NB_SCAN, 256, 0, stream>>>(counts, blksum, rowptr, cursor);
    k_dis_from_counts<<<nblk_nodes, 256, 0, stream>>>(counts, dis, rowptr);
    k_place<<<2048, 256, 0, stream>>>(esrc, edst, cursor, esorted);

    // layer 0
    k_rowgemm<F_IN><<<GB, 256, 0, stream>>>(x, W0, dis, u);
    k_gather_relu<<<2048, 256, 0, stream>>>(rowptr, esorted, u, dis, b0, h1);
    // layer 1
    k_rowgemm<HID><<<GB, 256, 0, stream>>>(h1, W1, dis, u);
    k_gather_relu<<<2048, 256, 0, stream>>>(rowptr, esorted, u, dis, b1, h2);
    // layer 2
    k_rowgemm<HID><<<GB, 256, 0, stream>>>(h2, W2, dis, u);
    k_gather_relu<<<2048, 256, 0, stream>>>(rowptr, esorted, u, dis, b2, h3);

    // JK concat + final linear (fused)
    k_linfused<<<GB, 256, 0, stream>>>(x, h1, h2, h3, Wl, bl, out);
}

// Round 8
// 701.355 us; speedup vs baseline: 1.7754x; 1.7754x over previous
//
#include <hip/hip_runtime.h>

// GCN 3-layer + JK-concat.  N=100000, E=1600000, F_IN=128, H=64, F_OUT=64.
//
// R7: fix R6's regression. R6 derived the column-half jh from threadIdx
// (divergent to the compiler) -> W pointer lost uniformity -> W fell off the
// scalar path (SGPR 112->48), per-lane vector W loads blew register pressure,
// acc spilled to scratch (WRITE_SIZE 25->248MB), 465us latency-bound.
// Fix: jh = blockIdx.x & 1 (block-uniform by construction -> SGPR), tiles
// distributed over blockIdx>>1 and local wave. acc[32]+buf fits in VGPRs,
// no spill, W rides s_loads, 3128 waves (~3/SIMD).
//
// Algebra: h_next[d] = relu( dis[d] * ( u[d] + sum_{s->d} u[s] ) + b ),
//          u = (h @ W) * dis[row],  dis = rsqrt(1 + indeg)

#define N_NODES 100000
#define N_EDGES 1600000
#define F_IN    128
#define HID     64
#define NB_SCAN 98          // ceil(N_NODES / 1024)

// ================= CSR build =================
__global__ void k_zero(int* __restrict__ p, int n) {
    int i = blockIdx.x * blockDim.x + threadIdx.x;
    if (i < n) p[i] = 0;
}

__global__ void k_hist(const int* __restrict__ dst, int* __restrict__ counts) {
    int stride = gridDim.x * blockDim.x;
    for (int e = blockIdx.x * blockDim.x + threadIdx.x; e < N_EDGES; e += stride)
        atomicAdd(&counts[dst[e]], 1);
}

__global__ void k_blocksum(const int* __restrict__ counts, int* __restrict__ blksum) {
    __shared__ int red[256];
    int b = blockIdx.x, t = threadIdx.x;
    int base = b * 1024 + t * 4;
    int s = 0;
    #pragma unroll
    for (int q = 0; q < 4; q++) { int idx = base + q; if (idx < N_NODES) s += counts[idx]; }
    red[t] = s; __syncthreads();
    for (int off = 128; off > 0; off >>= 1) {
        if (t < off) red[t] += red[t + off];
        __syncthreads();
    }
    if (t == 0) blksum[b] = red[0];
}

__global__ void k_scan_top(int* __restrict__ blksum) {   // 1 block, 128 threads
    __shared__ int s[128];
    int t = threadIdx.x;
    s[t] = (t < NB_SCAN) ? blksum[t] : 0;
    __syncthreads();
    for (int off = 1; off < 128; off <<= 1) {
        int v = (t >= off) ? s[t - off] : 0;
        __syncthreads();
        s[t] += v;
        __syncthreads();
    }
    if (t < NB_SCAN) blksum[t] = (t == 0) ? 0 : s[t - 1];   // exclusive
}

__global__ void k_scan_write(const int* __restrict__ counts, const int* __restrict__ blkoff,
                             int* __restrict__ rowptr, int* __restrict__ cursor) {
    __shared__ int ts[256];
    int b = blockIdx.x, t = threadIdx.x;
    int base = b * 1024 + t * 4;
    int c[4]; int s = 0;
    #pragma unroll
    for (int q = 0; q < 4; q++) { int idx = base + q; c[q] = (idx < N_NODES) ? counts[idx] : 0; s += c[q]; }
    ts[t] = s; __syncthreads();
    for (int off = 1; off < 256; off <<= 1) {
        int v = (t >= off) ? ts[t - off] : 0;
        __syncthreads();
        ts[t] += v;
        __syncthreads();
    }
    int run = blkoff[b] + ((t == 0) ? 0 : ts[t - 1]);
    #pragma unroll
    for (int q = 0; q < 4; q++) {
        int idx = base + q;
        if (idx < N_NODES) { rowptr[idx] = run; cursor[idx] = run; run += c[q]; }
    }
}

__global__ void k_dis_from_counts(const int* __restrict__ counts, float* __restrict__ dis,
                                  int* __restrict__ rowptr) {
    int i = blockIdx.x * blockDim.x + threadIdx.x;
    if (i < N_NODES) dis[i] = rsqrtf(1.0f + (float)counts[i]);
    if (i == 0) rowptr[N_NODES] = N_EDGES;
}

__global__ void k_place(const int* __restrict__ src, const int* __restrict__ dst,
                        int* __restrict__ cursor, int* __restrict__ esorted) {
    int stride = gridDim.x * blockDim.x;
    for (int e = blockIdx.x * blockDim.x + threadIdx.x; e < N_EDGES; e += stride) {
        int d = dst[e];
        int pos = atomicAdd(&cursor[d], 1);
        esorted[pos] = src[e];
    }
}

// ================= dense: lane = row, 32-col half per wave =================
// acc[j] += X[row][k] * W[k][jbase+j], j in [0,32), k in [0,K).
// W row stride 64; Wh = W + jbase MUST be wave-uniform (block-uniform here)
// so W stays on the scalar path. xb double-buffered for load/FMA overlap.
template<int K>
__device__ __forceinline__ void seg_accum32(const float* __restrict__ xr,
                                            const float* __restrict__ Wh,
                                            float (&acc)[32]) {
    float4 buf[4];
    #pragma unroll
    for (int q = 0; q < 4; q++)
        buf[q] = *reinterpret_cast<const float4*>(xr + 4 * q);
    #pragma unroll 1
    for (int k0 = 0; k0 < K; k0 += 16) {
        float xb[16];
        #pragma unroll
        for (int q = 0; q < 4; q++) {
            xb[4 * q + 0] = buf[q].x; xb[4 * q + 1] = buf[q].y;
            xb[4 * q + 2] = buf[q].z; xb[4 * q + 3] = buf[q].w;
        }
        if (k0 + 16 < K) {               // issue next tile's loads before FMAs
            #pragma unroll
            for (int q = 0; q < 4; q++)
                buf[q] = *reinterpret_cast<const float4*>(xr + k0 + 16 + 4 * q);
        }
        #pragma unroll
        for (int kk = 0; kk < 16; kk++) {
            const float* wk = Wh + (size_t)(k0 + kk) * 64;   // uniform -> s_load
            #pragma unroll
            for (int j = 0; j < 32; j++)
                acc[j] = fmaf(xb[kk], wk[j], acc[j]);
        }
    }
}

// u[r][jh*32:(jh+1)*32] = (X[r][:] @ W[:, jh-half]) * dis[r]
// jh = blockIdx.x & 1 -> block-uniform -> scalar W path.
template<int K>
__global__ __launch_bounds__(256, 4) void k_rowgemm(
        const float* __restrict__ X, const float* __restrict__ W,
        const float* __restrict__ dis, float* __restrict__ u) {
    const int lane = threadIdx.x & 63;
    const int lw   = threadIdx.x >> 6;           // local wave 0..3
    const int wpb  = blockDim.x >> 6;
    const int jh   = blockIdx.x & 1;             // BLOCK-uniform
    const float* Wh = W + jh * 32;
    const int ntiles  = (N_NODES + 63) / 64;
    const int tstride = (gridDim.x >> 1) * wpb;
    for (int tile = (blockIdx.x >> 1) * wpb + lw; tile < ntiles; tile += tstride) {
        int r  = tile * 64 + lane;
        int rc = r < N_NODES ? r : N_NODES - 1;
        const float* xr = X + (size_t)rc * K;
        float acc[32];
        #pragma unroll
        for (int j = 0; j < 32; j++) acc[j] = 0.f;
        seg_accum32<K>(xr, Wh, acc);
        if (r < N_NODES) {
            float dv = dis[r];
            float* orow = u + (size_t)r * 64 + jh * 32;
            #pragma unroll
            for (int j4 = 0; j4 < 8; j4++) {
                float4 st = { acc[4*j4] * dv, acc[4*j4+1] * dv,
                              acc[4*j4+2] * dv, acc[4*j4+3] * dv };
                *reinterpret_cast<float4*>(orow + 4 * j4) = st;
            }
        }
    }
}

// out[r][half] = bl[half] + x[r]@Wl[0:128,half] + h1@Wl[128:192,half]
//              + h2@Wl[192:256,half] + h3@Wl[256:320,half]
__global__ __launch_bounds__(256, 4) void k_linfused(
        const float* __restrict__ x,  const float* __restrict__ h1,
        const float* __restrict__ h2, const float* __restrict__ h3,
        const float* __restrict__ Wl, const float* __restrict__ bl,
        float* __restrict__ out) {
    const int lane = threadIdx.x & 63;
    const int lw   = threadIdx.x >> 6;
    const int wpb  = blockDim.x >> 6;
    const int jh   = blockIdx.x & 1;             // BLOCK-uniform
    const int ntiles  = (N_NODES + 63) / 64;
    const int tstride = (gridDim.x >> 1) * wpb;
    const float* blh = bl + jh * 32;
    for (int tile = (blockIdx.x >> 1) * wpb + lw; tile < ntiles; tile += tstride) {
        int r  = tile * 64 + lane;
        int rc = r < N_NODES ? r : N_NODES - 1;
        float acc[32];
        #pragma unroll
        for (int j = 0; j < 32; j++) acc[j] = blh[j];    // uniform -> s_load
        seg_accum32<F_IN>(x  + (size_t)rc * F_IN, Wl            + jh * 32, acc);
        seg_accum32<HID >(h1 + (size_t)rc * HID,  Wl + 128 * 64 + jh * 32, acc);
        seg_accum32<HID >(h2 + (size_t)rc * HID,  Wl + 192 * 64 + jh * 32, acc);
        seg_accum32<HID >(h3 + (size_t)rc * HID,  Wl + 256 * 64 + jh * 32, acc);
        if (r < N_NODES) {
            float* orow = out + (size_t)r * 64 + jh * 32;
            #pragma unroll
            for (int j4 = 0; j4 < 8; j4++) {
                float4 st = { acc[4*j4], acc[4*j4+1], acc[4*j4+2], acc[4*j4+3] };
                *reinterpret_cast<float4*>(orow + 4 * j4) = st;
            }
        }
    }
}

// ================= gather: h = relu(dis[d]*(u[d]+sum u[s]) + b) =================
__global__ __launch_bounds__(256) void k_gather_relu(
        const int* __restrict__ rowptr, const int* __restrict__ es,
        const float* __restrict__ u, const float* __restrict__ dis,
        const float* __restrict__ bias, float* __restrict__ hout) {
    const int lane = threadIdx.x & 63, wid = threadIdx.x >> 6, wpb = blockDim.x >> 6;
    const float bj = bias[lane];
    for (int d = blockIdx.x * wpb + wid; d < N_NODES; d += gridDim.x * wpb) {
        float a = u[(size_t)d * HID + lane];          // self loop
        int i = rowptr[d], end = rowptr[d + 1];
        for (; i + 4 <= end; i += 4) {
            int s0 = es[i], s1 = es[i + 1], s2 = es[i + 2], s3 = es[i + 3];
            float v0 = u[(size_t)s0 * HID + lane];
            float v1 = u[(size_t)s1 * HID + lane];
            float v2 = u[(size_t)s2 * HID + lane];
            float v3 = u[(size_t)s3 * HID + lane];
            a += v0; a += v1; a += v2; a += v3;
        }
        for (; i < end; i++) a += u[(size_t)es[i] * HID + lane];
        float v = fmaf(a, dis[d], bj);
        hout[(size_t)d * HID + lane] = v > 0.f ? v : 0.f;
    }
}

// ================= launch =================
extern "C" void kernel_launch(void* const* d_in, const int* in_sizes, int n_in,
                              void* d_out, int out_size, void* d_ws, size_t ws_size,
                              hipStream_t stream) {
    const float* x  = (const float*)d_in[0];
    const int*   ei = (const int*)d_in[1];      // edge_index [2, E] int32
    const float* W0 = (const float*)d_in[2];
    const float* b0 = (const float*)d_in[3];
    const float* W1 = (const float*)d_in[4];
    const float* b1 = (const float*)d_in[5];
    const float* W2 = (const float*)d_in[6];
    const float* b2 = (const float*)d_in[7];
    const float* Wl = (const float*)d_in[8];
    const float* bl = (const float*)d_in[9];
    float* out = (float*)d_out;

    const int* esrc = ei;
    const int* edst = ei + N_EDGES;

    // workspace layout (byte offsets; total ~110.5 MB)
    char* w = (char*)d_ws;
    float* dis     = (float*)(w);                       //   409,600 B
    float* u       = (float*)(w + 409600);              // 25,600,000
    float* h1      = (float*)(w + 26009600);            // 25,600,000
    float* h2      = (float*)(w + 51609600);            // 25,600,000
    float* h3      = (float*)(w + 77209600);            // 25,600,000
    int*   counts  = (int*)  (w + 102809600);           //    409,600
    int*   rowptr  = (int*)  (w + 103219200);           //    409,600 (N+1)
    int*   cursor  = (int*)  (w + 103628800);           //    409,600
    int*   esorted = (int*)  (w + 104038400);           //  6,400,000
    int*   blksum  = (int*)  (w + 110438400);           //        512

    const int nblk_nodes = (N_NODES + 255) / 256;
    const int GB = 782;   // even: 391 tile-groups x 2 col-halves; 4 waves/block

    // CSR build (ws re-poisoned each call, so rebuild every time)
    k_zero<<<nblk_nodes, 256, 0, stream>>>(counts, N_NODES);
    k_hist<<<2048, 256, 0, stream>>>(edst, counts);
    k_blocksum<<<NB_SCAN, 256, 0, stream>>>(counts, blksum);
    k_scan_top<<<1, 128, 0, stream>>>(blksum);
    k_scan_write<<<NB_SCAN, 256, 0, stream>>>(counts, blksum, rowptr, cursor);
    k_dis_from_counts<<<nblk_nodes, 256, 0, stream>>>(counts, dis, rowptr);
    k_place<<<2048, 256, 0, stream>>>(esrc, edst, cursor, esorted);

    // layer 0
    k_rowgemm<F_IN><<<GB, 256, 0, stream>>>(x, W0, dis, u);
    k_gather_relu<<<2048, 256, 0, stream>>>(rowptr, esorted, u, dis, b0, h1);
    // layer 1
    k_rowgemm<HID><<<GB, 256, 0, stream>>>(h1, W1, dis, u);
    k_gather_relu<<<2048, 256, 0, stream>>>(rowptr, esorted, u, dis, b1, h2);
    // layer 2
    k_rowgemm<HID><<<GB, 256, 0, stream>>>(h2, W2, dis, u);
    k_gather_relu<<<2048, 256, 0, stream>>>(rowptr, esorted, u, dis, b2, h3);

    // JK concat + final linear (fused)
    k_linfused<<<GB, 256, 0, stream>>>(x, h1, h2, h3, Wl, bl, out);
}

// Round 9
// 666.856 us; speedup vs baseline: 1.8672x; 1.0517x over previous
//
#include <hip/hip_runtime.h>

// GCN 3-layer + JK-concat.  N=100000, E=1600000, F_IN=128, H=64, F_OUT=64.
//
// R8: kill k_place (134us, top dispatch). Its counters: WRITE_SIZE=107MB for a
// 6.4MB logical write -> every random 4B esorted store dirtied a full line.
// Replace with 2-level bucket partition: bucket = dst>>7 (782 x 128 nodes);
// (1) bucket hist + scan, (2) k_partition writes (src,dst) pairs into
// per-bucket streams (range-claim: one global atomic per block x bucket,
// then sequential writes), (3) k_local_place: one block per bucket, per-node
// cursors in LDS, esorted writes confined to the bucket's ~8KB rowptr window
// (L2-hot full lines). pairs aliases u (u written only after build).
// Dense kernels unchanged from R7 (jh block-uniform, W on scalar path).
//
// Algebra: h_next[d] = relu( dis[d] * ( u[d] + sum_{s->d} u[s] ) + b ),
//          u = (h @ W) * dis[row],  dis = rsqrt(1 + indeg)

#define N_NODES 100000
#define N_EDGES 1600000
#define F_IN    128
#define HID     64
#define NB_SCAN 98          // ceil(N_NODES / 1024)
#define NBUCK   782         // ceil(N_NODES / 128)
#define NPART   128         // partition blocks
#define EPB     12500       // edges per partition block (128*12500 = 1.6M exact)

// ================= CSR build =================
__global__ void k_zero(int* __restrict__ p, int n) {
    int i = blockIdx.x * blockDim.x + threadIdx.x;
    if (i < n) p[i] = 0;
}

__global__ void k_hist(const int* __restrict__ dst, int* __restrict__ counts) {
    int stride = gridDim.x * blockDim.x;
    for (int e = blockIdx.x * blockDim.x + threadIdx.x; e < N_EDGES; e += stride)
        atomicAdd(&counts[dst[e]], 1);
}

__global__ void k_blocksum(const int* __restrict__ counts, int* __restrict__ blksum) {
    __shared__ int red[256];
    int b = blockIdx.x, t = threadIdx.x;
    int base = b * 1024 + t * 4;
    int s = 0;
    #pragma unroll
    for (int q = 0; q < 4; q++) { int idx = base + q; if (idx < N_NODES) s += counts[idx]; }
    red[t] = s; __syncthreads();
    for (int off = 128; off > 0; off >>= 1) {
        if (t < off) red[t] += red[t + off];
        __syncthreads();
    }
    if (t == 0) blksum[b] = red[0];
}

__global__ void k_scan_top(int* __restrict__ blksum) {   // 1 block, 128 threads
    __shared__ int s[128];
    int t = threadIdx.x;
    s[t] = (t < NB_SCAN) ? blksum[t] : 0;
    __syncthreads();
    for (int off = 1; off < 128; off <<= 1) {
        int v = (t >= off) ? s[t - off] : 0;
        __syncthreads();
        s[t] += v;
        __syncthreads();
    }
    if (t < NB_SCAN) blksum[t] = (t == 0) ? 0 : s[t - 1];   // exclusive
}

__global__ void k_scan_write(const int* __restrict__ counts, const int* __restrict__ blkoff,
                             int* __restrict__ rowptr) {
    __shared__ int ts[256];
    int b = blockIdx.x, t = threadIdx.x;
    int base = b * 1024 + t * 4;
    int c[4]; int s = 0;
    #pragma unroll
    for (int q = 0; q < 4; q++) { int idx = base + q; c[q] = (idx < N_NODES) ? counts[idx] : 0; s += c[q]; }
    ts[t] = s; __syncthreads();
    for (int off = 1; off < 256; off <<= 1) {
        int v = (t >= off) ? ts[t - off] : 0;
        __syncthreads();
        ts[t] += v;
        __syncthreads();
    }
    int run = blkoff[b] + ((t == 0) ? 0 : ts[t - 1]);
    #pragma unroll
    for (int q = 0; q < 4; q++) {
        int idx = base + q;
        if (idx < N_NODES) { rowptr[idx] = run; run += c[q]; }
    }
}

__global__ void k_dis_from_counts(const int* __restrict__ counts, float* __restrict__ dis,
                                  int* __restrict__ rowptr) {
    int i = blockIdx.x * blockDim.x + threadIdx.x;
    if (i < N_NODES) dis[i] = rsqrtf(1.0f + (float)counts[i]);
    if (i == 0) rowptr[N_NODES] = N_EDGES;
}

// ---- bucket partition (replaces global k_place scatter) ----
__global__ __launch_bounds__(256) void k_bucket_hist(const int* __restrict__ dst,
                                                     int* __restrict__ bhist) {
    __shared__ int hist[NBUCK];
    for (int i = threadIdx.x; i < NBUCK; i += blockDim.x) hist[i] = 0;
    __syncthreads();
    const int e0 = blockIdx.x * EPB;
    for (int e = e0 + threadIdx.x; e < e0 + EPB; e += blockDim.x)
        atomicAdd(&hist[dst[e] >> 7], 1);
    __syncthreads();
    for (int i = threadIdx.x; i < NBUCK; i += blockDim.x)
        if (hist[i]) atomicAdd(&bhist[i], hist[i]);
}

__global__ void k_bucket_scan(int* __restrict__ bhist, int* __restrict__ bcursor) {
    __shared__ int s[1024];      // 1 block, 1024 threads
    int t = threadIdx.x;
    s[t] = (t < NBUCK) ? bhist[t] : 0;
    __syncthreads();
    for (int off = 1; off < 1024; off <<= 1) {
        int v = (t >= off) ? s[t - off] : 0;
        __syncthreads();
        s[t] += v;
        __syncthreads();
    }
    if (t < NBUCK) {
        int excl = (t == 0) ? 0 : s[t - 1];
        bhist[t] = excl;          // bucket start
        bcursor[t] = excl;        // running cursor for partition claims
    }
    if (t == NBUCK - 1) bhist[NBUCK] = s[t];   // = N_EDGES
}

__global__ __launch_bounds__(256) void k_partition(
        const int* __restrict__ src, const int* __restrict__ dst,
        int* __restrict__ bcursor, int2* __restrict__ pairs) {
    __shared__ int hist[NBUCK];
    __shared__ int cur[NBUCK];
    for (int i = threadIdx.x; i < NBUCK; i += blockDim.x) hist[i] = 0;
    __syncthreads();
    const int e0 = blockIdx.x * EPB;
    for (int e = e0 + threadIdx.x; e < e0 + EPB; e += blockDim.x)
        atomicAdd(&hist[dst[e] >> 7], 1);
    __syncthreads();
    for (int i = threadIdx.x; i < NBUCK; i += blockDim.x) {
        int c = hist[i];
        cur[i] = c ? atomicAdd(&bcursor[i], c) : 0;   // claim contiguous range
    }
    __syncthreads();
    for (int e = e0 + threadIdx.x; e < e0 + EPB; e += blockDim.x) {
        int d = dst[e];
        int pos = atomicAdd(&cur[d >> 7], 1);
        pairs[pos] = make_int2(src[e], d);
    }
}

__global__ __launch_bounds__(256) void k_local_place(
        const int2* __restrict__ pairs, const int* __restrict__ bstart,
        const int* __restrict__ rowptr, int* __restrict__ esorted) {
    __shared__ int cur[128];
    const int b = blockIdx.x, nbase = b << 7;
    for (int i = threadIdx.x; i < 128; i += blockDim.x) {
        int node = nbase + i;
        cur[i] = (node < N_NODES) ? rowptr[node] : 0;
    }
    __syncthreads();
    const int e0 = bstart[b], e1 = bstart[b + 1];
    for (int e = e0 + threadIdx.x; e < e1; e += blockDim.x) {
        int2 p = pairs[e];
        int pos = atomicAdd(&cur[p.y - nbase], 1);
        esorted[pos] = p.x;
    }
}

// ================= dense: lane = row, 32-col half per wave =================
template<int K>
__device__ __forceinline__ void seg_accum32(const float* __restrict__ xr,
                                            const float* __restrict__ Wh,
                                            float (&acc)[32]) {
    float4 buf[4];
    #pragma unroll
    for (int q = 0; q < 4; q++)
        buf[q] = *reinterpret_cast<const float4*>(xr + 4 * q);
    #pragma unroll 1
    for (int k0 = 0; k0 < K; k0 += 16) {
        float xb[16];
        #pragma unroll
        for (int q = 0; q < 4; q++) {
            xb[4 * q + 0] = buf[q].x; xb[4 * q + 1] = buf[q].y;
            xb[4 * q + 2] = buf[q].z; xb[4 * q + 3] = buf[q].w;
        }
        if (k0 + 16 < K) {               // issue next tile's loads before FMAs
            #pragma unroll
            for (int q = 0; q < 4; q++)
                buf[q] = *reinterpret_cast<const float4*>(xr + k0 + 16 + 4 * q);
        }
        #pragma unroll
        for (int kk = 0; kk < 16; kk++) {
            const float* wk = Wh + (size_t)(k0 + kk) * 64;   // uniform -> s_load
            #pragma unroll
            for (int j = 0; j < 32; j++)
                acc[j] = fmaf(xb[kk], wk[j], acc[j]);
        }
    }
}

template<int K>
__global__ __launch_bounds__(256, 4) void k_rowgemm(
        const float* __restrict__ X, const float* __restrict__ W,
        const float* __restrict__ dis, float* __restrict__ u) {
    const int lane = threadIdx.x & 63;
    const int lw   = threadIdx.x >> 6;
    const int wpb  = blockDim.x >> 6;
    const int jh   = blockIdx.x & 1;             // BLOCK-uniform
    const float* Wh = W + jh * 32;
    const int ntiles  = (N_NODES + 63) / 64;
    const int tstride = (gridDim.x >> 1) * wpb;
    for (int tile = (blockIdx.x >> 1) * wpb + lw; tile < ntiles; tile += tstride) {
        int r  = tile * 64 + lane;
        int rc = r < N_NODES ? r : N_NODES - 1;
        const float* xr = X + (size_t)rc * K;
        float acc[32];
        #pragma unroll
        for (int j = 0; j < 32; j++) acc[j] = 0.f;
        seg_accum32<K>(xr, Wh, acc);
        if (r < N_NODES) {
            float dv = dis[r];
            float* orow = u + (size_t)r * 64 + jh * 32;
            #pragma unroll
            for (int j4 = 0; j4 < 8; j4++) {
                float4 st = { acc[4*j4] * dv, acc[4*j4+1] * dv,
                              acc[4*j4+2] * dv, acc[4*j4+3] * dv };
                *reinterpret_cast<float4*>(orow + 4 * j4) = st;
            }
        }
    }
}

__global__ __launch_bounds__(256, 4) void k_linfused(
        const float* __restrict__ x,  const float* __restrict__ h1,
        const float* __restrict__ h2, const float* __restrict__ h3,
        const float* __restrict__ Wl, const float* __restrict__ bl,
        float* __restrict__ out) {
    const int lane = threadIdx.x & 63;
    const int lw   = threadIdx.x >> 6;
    const int wpb  = blockDim.x >> 6;
    const int jh   = blockIdx.x & 1;             // BLOCK-uniform
    const int ntiles  = (N_NODES + 63) / 64;
    const int tstride = (gridDim.x >> 1) * wpb;
    const float* blh = bl + jh * 32;
    for (int tile = (blockIdx.x >> 1) * wpb + lw; tile < ntiles; tile += tstride) {
        int r  = tile * 64 + lane;
        int rc = r < N_NODES ? r : N_NODES - 1;
        float acc[32];
        #pragma unroll
        for (int j = 0; j < 32; j++) acc[j] = blh[j];    // uniform -> s_load
        seg_accum32<F_IN>(x  + (size_t)rc * F_IN, Wl            + jh * 32, acc);
        seg_accum32<HID >(h1 + (size_t)rc * HID,  Wl + 128 * 64 + jh * 32, acc);
        seg_accum32<HID >(h2 + (size_t)rc * HID,  Wl + 192 * 64 + jh * 32, acc);
        seg_accum32<HID >(h3 + (size_t)rc * HID,  Wl + 256 * 64 + jh * 32, acc);
        if (r < N_NODES) {
            float* orow = out + (size_t)r * 64 + jh * 32;
            #pragma unroll
            for (int j4 = 0; j4 < 8; j4++) {
                float4 st = { acc[4*j4], acc[4*j4+1], acc[4*j4+2], acc[4*j4+3] };
                *reinterpret_cast<float4*>(orow + 4 * j4) = st;
            }
        }
    }
}

// ================= gather: h = relu(dis[d]*(u[d]+sum u[s]) + b) =================
__global__ __launch_bounds__(256) void k_gather_relu(
        const int* __restrict__ rowptr, const int* __restrict__ es,
        const float* __restrict__ u, const float* __restrict__ dis,
        const float* __restrict__ bias, float* __restrict__ hout) {
    const int lane = threadIdx.x & 63, wid = threadIdx.x >> 6, wpb = blockDim.x >> 6;
    const float bj = bias[lane];
    for (int d = blockIdx.x * wpb + wid; d < N_NODES; d += gridDim.x * wpb) {
        float a = u[(size_t)d * HID + lane];          // self loop
        int i = rowptr[d], end = rowptr[d + 1];
        for (; i + 4 <= end; i += 4) {
            int s0 = es[i], s1 = es[i + 1], s2 = es[i + 2], s3 = es[i + 3];
            float v0 = u[(size_t)s0 * HID + lane];
            float v1 = u[(size_t)s1 * HID + lane];
            float v2 = u[(size_t)s2 * HID + lane];
            float v3 = u[(size_t)s3 * HID + lane];
            a += v0; a += v1; a += v2; a += v3;
        }
        for (; i < end; i++) a += u[(size_t)es[i] * HID + lane];
        float v = fmaf(a, dis[d], bj);
        hout[(size_t)d * HID + lane] = v > 0.f ? v : 0.f;
    }
}

// ================= launch =================
extern "C" void kernel_launch(void* const* d_in, const int* in_sizes, int n_in,
                              void* d_out, int out_size, void* d_ws, size_t ws_size,
                              hipStream_t stream) {
    const float* x  = (const float*)d_in[0];
    const int*   ei = (const int*)d_in[1];      // edge_index [2, E] int32
    const float* W0 = (const float*)d_in[2];
    const float* b0 = (const float*)d_in[3];
    const float* W1 = (const float*)d_in[4];
    const float* b1 = (const float*)d_in[5];
    const float* W2 = (const float*)d_in[6];
    const float* b2 = (const float*)d_in[7];
    const float* Wl = (const float*)d_in[8];
    const float* bl = (const float*)d_in[9];
    float* out = (float*)d_out;

    const int* esrc = ei;
    const int* edst = ei + N_EDGES;

    // workspace layout (byte offsets; total ~110.5 MB, same high-water as R7)
    char* w = (char*)d_ws;
    float* dis     = (float*)(w);                       //   409,600 B
    float* u       = (float*)(w + 409600);              // 25,600,000
    float* h1      = (float*)(w + 26009600);            // 25,600,000
    float* h2      = (float*)(w + 51609600);            // 25,600,000
    float* h3      = (float*)(w + 77209600);            // 25,600,000
    int*   counts  = (int*)  (w + 102809600);           //    409,600
    int*   rowptr  = (int*)  (w + 103219200);           //    409,600 (N+1)
    int*   bhist   = (int*)  (w + 103628800);           //      4,096 (NBUCK+1)
    int*   bcursor = (int*)  (w + 103632896);           //      4,096
    int*   esorted = (int*)  (w + 104038400);           //  6,400,000
    int*   blksum  = (int*)  (w + 110438400);           //        512
    int2*  pairs   = (int2*) (w + 409600);              // aliases u (build-only)

    const int nblk_nodes = (N_NODES + 255) / 256;
    const int GB = 782;   // even: 391 tile-groups x 2 col-halves; 4 waves/block

    // CSR build (ws re-poisoned each call, so rebuild every time)
    k_zero<<<nblk_nodes, 256, 0, stream>>>(counts, N_NODES);
    k_zero<<<4, 256, 0, stream>>>(bhist, 1024);
    k_hist<<<2048, 256, 0, stream>>>(edst, counts);
    k_blocksum<<<NB_SCAN, 256, 0, stream>>>(counts, blksum);
    k_scan_top<<<1, 128, 0, stream>>>(blksum);
    k_scan_write<<<NB_SCAN, 256, 0, stream>>>(counts, blksum, rowptr);
    k_dis_from_counts<<<nblk_nodes, 256, 0, stream>>>(counts, dis, rowptr);
    k_bucket_hist<<<NPART, 256, 0, stream>>>(edst, bhist);
    k_bucket_scan<<<1, 1024, 0, stream>>>(bhist, bcursor);
    k_partition<<<NPART, 256, 0, stream>>>(esrc, edst, bcursor, pairs);
    k_local_place<<<NBUCK, 256, 0, stream>>>(pairs, bhist, rowptr, esorted);

    // layer 0
    k_rowgemm<F_IN><<<GB, 256, 0, stream>>>(x, W0, dis, u);
    k_gather_relu<<<2048, 256, 0, stream>>>(rowptr, esorted, u, dis, b0, h1);
    // layer 1
    k_rowgemm<HID><<<GB, 256, 0, stream>>>(h1, W1, dis, u);
    k_gather_relu<<<2048, 256, 0, stream>>>(rowptr, esorted, u, dis, b1, h2);
    // layer 2
    k_rowgemm<HID><<<GB, 256, 0, stream>>>(h2, W2, dis, u);
    k_gather_relu<<<2048, 256, 0, stream>>>(rowptr, esorted, u, dis, b2, h3);

    // JK concat + final linear (fused)
    k_linfused<<<GB, 256, 0, stream>>>(x, h1, h2, h3, Wl, bl, out);
}

// Round 10
// 594.052 us; speedup vs baseline: 2.0960x; 1.1226x over previous
//
#include <hip/hip_runtime.h>

// GCN 3-layer + JK-concat.  N=100000, E=1600000, F_IN=128, H=64, F_OUT=64.
//
// R9: LDS-staged dense kernels. R9 counters: k_linfused 97us, VALUBusy 28.6%
// (= FMA floor exactly), FETCH=128MB=logical at only 1.6TB/s -> request-rate
// bound: lane=row made every float4 load a 64-way gather (64 lines/instr).
// Now: block=4 waves=64 rows; X staged to LDS in 32-col chunks via coalesced
// loads (8 lines/instr), compute lane=row from LDS (pad 33 -> 2-way banks,
// free). Each wave does 16 output cols; jbase forced wave-uniform with
// readfirstlane so W stays on the scalar path (R6 lesson). CSR build,
// bucket partition, and gather unchanged from R8.
//
// Algebra: h_next[d] = relu( dis[d] * ( u[d] + sum_{s->d} u[s] ) + b ),
//          u = (h @ W) * dis[row],  dis = rsqrt(1 + indeg)

#define N_NODES 100000
#define N_EDGES 1600000
#define F_IN    128
#define HID     64
#define NB_SCAN 98          // ceil(N_NODES / 1024)
#define NBUCK   782         // ceil(N_NODES / 128)
#define NPART   128         // partition blocks
#define EPB     12500       // edges per partition block (128*12500 = 1.6M exact)
#define NTILES  1563        // ceil(N_NODES / 64)

// ================= CSR build =================
__global__ void k_zero(int* __restrict__ p, int n) {
    int i = blockIdx.x * blockDim.x + threadIdx.x;
    if (i < n) p[i] = 0;
}

__global__ void k_hist(const int* __restrict__ dst, int* __restrict__ counts) {
    int stride = gridDim.x * blockDim.x;
    for (int e = blockIdx.x * blockDim.x + threadIdx.x; e < N_EDGES; e += stride)
        atomicAdd(&counts[dst[e]], 1);
}

__global__ void k_blocksum(const int* __restrict__ counts, int* __restrict__ blksum) {
    __shared__ int red[256];
    int b = blockIdx.x, t = threadIdx.x;
    int base = b * 1024 + t * 4;
    int s = 0;
    #pragma unroll
    for (int q = 0; q < 4; q++) { int idx = base + q; if (idx < N_NODES) s += counts[idx]; }
    red[t] = s; __syncthreads();
    for (int off = 128; off > 0; off >>= 1) {
        if (t < off) red[t] += red[t + off];
        __syncthreads();
    }
    if (t == 0) blksum[b] = red[0];
}

__global__ void k_scan_top(int* __restrict__ blksum) {   // 1 block, 128 threads
    __shared__ int s[128];
    int t = threadIdx.x;
    s[t] = (t < NB_SCAN) ? blksum[t] : 0;
    __syncthreads();
    for (int off = 1; off < 128; off <<= 1) {
        int v = (t >= off) ? s[t - off] : 0;
        __syncthreads();
        s[t] += v;
        __syncthreads();
    }
    if (t < NB_SCAN) blksum[t] = (t == 0) ? 0 : s[t - 1];   // exclusive
}

__global__ void k_scan_write(const int* __restrict__ counts, const int* __restrict__ blkoff,
                             int* __restrict__ rowptr) {
    __shared__ int ts[256];
    int b = blockIdx.x, t = threadIdx.x;
    int base = b * 1024 + t * 4;
    int c[4]; int s = 0;
    #pragma unroll
    for (int q = 0; q < 4; q++) { int idx = base + q; c[q] = (idx < N_NODES) ? counts[idx] : 0; s += c[q]; }
    ts[t] = s; __syncthreads();
    for (int off = 1; off < 256; off <<= 1) {
        int v = (t >= off) ? ts[t - off] : 0;
        __syncthreads();
        ts[t] += v;
        __syncthreads();
    }
    int run = blkoff[b] + ((t == 0) ? 0 : ts[t - 1]);
    #pragma unroll
    for (int q = 0; q < 4; q++) {
        int idx = base + q;
        if (idx < N_NODES) { rowptr[idx] = run; run += c[q]; }
    }
}

__global__ void k_dis_from_counts(const int* __restrict__ counts, float* __restrict__ dis,
                                  int* __restrict__ rowptr) {
    int i = blockIdx.x * blockDim.x + threadIdx.x;
    if (i < N_NODES) dis[i] = rsqrtf(1.0f + (float)counts[i]);
    if (i == 0) rowptr[N_NODES] = N_EDGES;
}

// ---- bucket partition ----
__global__ __launch_bounds__(256) void k_bucket_hist(const int* __restrict__ dst,
                                                     int* __restrict__ bhist) {
    __shared__ int hist[NBUCK];
    for (int i = threadIdx.x; i < NBUCK; i += blockDim.x) hist[i] = 0;
    __syncthreads();
    const int e0 = blockIdx.x * EPB;
    for (int e = e0 + threadIdx.x; e < e0 + EPB; e += blockDim.x)
        atomicAdd(&hist[dst[e] >> 7], 1);
    __syncthreads();
    for (int i = threadIdx.x; i < NBUCK; i += blockDim.x)
        if (hist[i]) atomicAdd(&bhist[i], hist[i]);
}

__global__ void k_bucket_scan(int* __restrict__ bhist, int* __restrict__ bcursor) {
    __shared__ int s[1024];      // 1 block, 1024 threads
    int t = threadIdx.x;
    s[t] = (t < NBUCK) ? bhist[t] : 0;
    __syncthreads();
    for (int off = 1; off < 1024; off <<= 1) {
        int v = (t >= off) ? s[t - off] : 0;
        __syncthreads();
        s[t] += v;
        __syncthreads();
    }
    if (t < NBUCK) {
        int excl = (t == 0) ? 0 : s[t - 1];
        bhist[t] = excl;          // bucket start
        bcursor[t] = excl;        // running cursor for partition claims
    }
    if (t == NBUCK - 1) bhist[NBUCK] = s[t];   // = N_EDGES
}

__global__ __launch_bounds__(256) void k_partition(
        const int* __restrict__ src, const int* __restrict__ dst,
        int* __restrict__ bcursor, int2* __restrict__ pairs) {
    __shared__ int hist[NBUCK];
    __shared__ int cur[NBUCK];
    for (int i = threadIdx.x; i < NBUCK; i += blockDim.x) hist[i] = 0;
    __syncthreads();
    const int e0 = blockIdx.x * EPB;
    for (int e = e0 + threadIdx.x; e < e0 + EPB; e += blockDim.x)
        atomicAdd(&hist[dst[e] >> 7], 1);
    __syncthreads();
    for (int i = threadIdx.x; i < NBUCK; i += blockDim.x) {
        int c = hist[i];
        cur[i] = c ? atomicAdd(&bcursor[i], c) : 0;   // claim contiguous range
    }
    __syncthreads();
    for (int e = e0 + threadIdx.x; e < e0 + EPB; e += blockDim.x) {
        int d = dst[e];
        int pos = atomicAdd(&cur[d >> 7], 1);
        pairs[pos] = make_int2(src[e], d);
    }
}

__global__ __launch_bounds__(256) void k_local_place(
        const int2* __restrict__ pairs, const int* __restrict__ bstart,
        const int* __restrict__ rowptr, int* __restrict__ esorted) {
    __shared__ int cur[128];
    const int b = blockIdx.x, nbase = b << 7;
    for (int i = threadIdx.x; i < 128; i += blockDim.x) {
        int node = nbase + i;
        cur[i] = (node < N_NODES) ? rowptr[node] : 0;
    }
    __syncthreads();
    const int e0 = bstart[b], e1 = bstart[b + 1];
    for (int e = e0 + threadIdx.x; e < e1; e += blockDim.x) {
        int2 p = pairs[e];
        int pos = atomicAdd(&cur[p.y - nbase], 1);
        esorted[pos] = p.x;
    }
}

// ================= dense: LDS-staged 64-row tile, wave = 16-col slice =================
// Stage Xseg[64 rows][32-col chunk] coalesced into xs, then lane=row computes
// acc[j] += xs[lane][k] * Wseg[k][jbase+j] with W on the scalar path.
template<int K>
__device__ __forceinline__ void seg_staged(
        const float* __restrict__ Xseg, const float* __restrict__ Wseg,
        float* __restrict__ xs /*[64*33]*/, int r0, int lane, int jbase,
        float (&acc)[16]) {
    for (int kc = 0; kc < K; kc += 32) {
        #pragma unroll
        for (int i = 0; i < 2; ++i) {
            int f = threadIdx.x + i * 256;          // 512 float4 = 64 rows x 8
            int row = f >> 3, c4 = f & 7;
            int gr = r0 + row; if (gr >= N_NODES) gr = N_NODES - 1;
            float4 v = *reinterpret_cast<const float4*>(Xseg + (size_t)gr * K + kc + c4 * 4);
            float* dst = xs + row * 33 + c4 * 4;
            dst[0] = v.x; dst[1] = v.y; dst[2] = v.z; dst[3] = v.w;
        }
        __syncthreads();
        const float* xrow = xs + lane * 33;
        #pragma unroll 8
        for (int kk = 0; kk < 32; ++kk) {
            float xv = xrow[kk];
            const float* wk = Wseg + (size_t)(kc + kk) * 64 + jbase;  // uniform -> s_load
            #pragma unroll
            for (int j = 0; j < 16; ++j) acc[j] = fmaf(xv, wk[j], acc[j]);
        }
        __syncthreads();
    }
}

// u[r][jbase:jbase+16] = (X[r][:] @ W[:,16-slice]) * dis[r]
template<int K>
__global__ __launch_bounds__(256, 6) void k_rowgemm(
        const float* __restrict__ X, const float* __restrict__ W,
        const float* __restrict__ dis, float* __restrict__ u) {
    __shared__ float xs[64 * 33];       // 8448 B
    const int lane  = threadIdx.x & 63;
    const int jbase = __builtin_amdgcn_readfirstlane((threadIdx.x >> 6) * 16);
    const int r0    = blockIdx.x * 64;
    float acc[16];
    #pragma unroll
    for (int j = 0; j < 16; ++j) acc[j] = 0.f;
    seg_staged<K>(X, W, xs, r0, lane, jbase, acc);
    int r = r0 + lane;
    if (r < N_NODES) {
        float dv = dis[r];
        float* orow = u + (size_t)r * 64 + jbase;
        #pragma unroll
        for (int j4 = 0; j4 < 4; ++j4) {
            float4 st = { acc[4*j4] * dv, acc[4*j4+1] * dv,
                          acc[4*j4+2] * dv, acc[4*j4+3] * dv };
            *reinterpret_cast<float4*>(orow + 4 * j4) = st;
        }
    }
}

// out[r][16-slice] = bl + x@Wl[0:128] + h1@Wl[128:192] + h2@Wl[192:256] + h3@Wl[256:320]
__global__ __launch_bounds__(256, 6) void k_linfused(
        const float* __restrict__ x,  const float* __restrict__ h1,
        const float* __restrict__ h2, const float* __restrict__ h3,
        const float* __restrict__ Wl, const float* __restrict__ bl,
        float* __restrict__ out) {
    __shared__ float xs[64 * 33];
    const int lane  = threadIdx.x & 63;
    const int jbase = __builtin_amdgcn_readfirstlane((threadIdx.x >> 6) * 16);
    const int r0    = blockIdx.x * 64;
    float acc[16];
    const float* blh = bl + jbase;
    #pragma unroll
    for (int j = 0; j < 16; ++j) acc[j] = blh[j];        // uniform -> s_load
    seg_staged<F_IN>(x,  Wl,            xs, r0, lane, jbase, acc);
    seg_staged<HID >(h1, Wl + 128 * 64, xs, r0, lane, jbase, acc);
    seg_staged<HID >(h2, Wl + 192 * 64, xs, r0, lane, jbase, acc);
    seg_staged<HID >(h3, Wl + 256 * 64, xs, r0, lane, jbase, acc);
    int r = r0 + lane;
    if (r < N_NODES) {
        float* orow = out + (size_t)r * 64 + jbase;
        #pragma unroll
        for (int j4 = 0; j4 < 4; ++j4) {
            float4 st = { acc[4*j4], acc[4*j4+1], acc[4*j4+2], acc[4*j4+3] };
            *reinterpret_cast<float4*>(orow + 4 * j4) = st;
        }
    }
}

// ================= gather: h = relu(dis[d]*(u[d]+sum u[s]) + b) =================
__global__ __launch_bounds__(256) void k_gather_relu(
        const int* __restrict__ rowptr, const int* __restrict__ es,
        const float* __restrict__ u, const float* __restrict__ dis,
        const float* __restrict__ bias, float* __restrict__ hout) {
    const int lane = threadIdx.x & 63, wid = threadIdx.x >> 6, wpb = blockDim.x >> 6;
    const float bj = bias[lane];
    for (int d = blockIdx.x * wpb + wid; d < N_NODES; d += gridDim.x * wpb) {
        float a = u[(size_t)d * HID + lane];          // self loop
        int i = rowptr[d], end = rowptr[d + 1];
        for (; i + 4 <= end; i += 4) {
            int s0 = es[i], s1 = es[i + 1], s2 = es[i + 2], s3 = es[i + 3];
            float v0 = u[(size_t)s0 * HID + lane];
            float v1 = u[(size_t)s1 * HID + lane];
            float v2 = u[(size_t)s2 * HID + lane];
            float v3 = u[(size_t)s3 * HID + lane];
            a += v0; a += v1; a += v2; a += v3;
        }
        for (; i < end; i++) a += u[(size_t)es[i] * HID + lane];
        float v = fmaf(a, dis[d], bj);
        hout[(size_t)d * HID + lane] = v > 0.f ? v : 0.f;
    }
}

// ================= launch =================
extern "C" void kernel_launch(void* const* d_in, const int* in_sizes, int n_in,
                              void* d_out, int out_size, void* d_ws, size_t ws_size,
                              hipStream_t stream) {
    const float* x  = (const float*)d_in[0];
    const int*   ei = (const int*)d_in[1];      // edge_index [2, E] int32
    const float* W0 = (const float*)d_in[2];
    const float* b0 = (const float*)d_in[3];
    const float* W1 = (const float*)d_in[4];
    const float* b1 = (const float*)d_in[5];
    const float* W2 = (const float*)d_in[6];
    const float* b2 = (const float*)d_in[7];
    const float* Wl = (const float*)d_in[8];
    const float* bl = (const float*)d_in[9];
    float* out = (float*)d_out;

    const int* esrc = ei;
    const int* edst = ei + N_EDGES;

    // workspace layout (byte offsets; total ~110.5 MB)
    char* w = (char*)d_ws;
    float* dis     = (float*)(w);                       //   409,600 B
    float* u       = (float*)(w + 409600);              // 25,600,000
    float* h1      = (float*)(w + 26009600);            // 25,600,000
    float* h2      = (float*)(w + 51609600);            // 25,600,000
    float* h3      = (float*)(w + 77209600);            // 25,600,000
    int*   counts  = (int*)  (w + 102809600);           //    409,600
    int*   rowptr  = (int*)  (w + 103219200);           //    409,600 (N+1)
    int*   bhist   = (int*)  (w + 103628800);           //      4,096 (NBUCK+1)
    int*   bcursor = (int*)  (w + 103632896);           //      4,096
    int*   esorted = (int*)  (w + 104038400);           //  6,400,000
    int*   blksum  = (int*)  (w + 110438400);           //        512
    int2*  pairs   = (int2*) (w + 409600);              // aliases u (build-only)

    const int nblk_nodes = (N_NODES + 255) / 256;

    // CSR build (ws re-poisoned each call, so rebuild every time)
    k_zero<<<nblk_nodes, 256, 0, stream>>>(counts, N_NODES);
    k_zero<<<4, 256, 0, stream>>>(bhist, 1024);
    k_hist<<<2048, 256, 0, stream>>>(edst, counts);
    k_blocksum<<<NB_SCAN, 256, 0, stream>>>(counts, blksum);
    k_scan_top<<<1, 128, 0, stream>>>(blksum);
    k_scan_write<<<NB_SCAN, 256, 0, stream>>>(counts, blksum, rowptr);
    k_dis_from_counts<<<nblk_nodes, 256, 0, stream>>>(counts, dis, rowptr);
    k_bucket_hist<<<NPART, 256, 0, stream>>>(edst, bhist);
    k_bucket_scan<<<1, 1024, 0, stream>>>(bhist, bcursor);
    k_partition<<<NPART, 256, 0, stream>>>(esrc, edst, bcursor, pairs);
    k_local_place<<<NBUCK, 256, 0, stream>>>(pairs, bhist, rowptr, esorted);

    // layer 0
    k_rowgemm<F_IN><<<NTILES, 256, 0, stream>>>(x, W0, dis, u);
    k_gather_relu<<<2048, 256, 0, stream>>>(rowptr, esorted, u, dis, b0, h1);
    // layer 1
    k_rowgemm<HID><<<NTILES, 256, 0, stream>>>(h1, W1, dis, u);
    k_gather_relu<<<2048, 256, 0, stream>>>(rowptr, esorted, u, dis, b1, h2);
    // layer 2
    k_rowgemm<HID><<<NTILES, 256, 0, stream>>>(h2, W2, dis, u);
    k_gather_relu<<<2048, 256, 0, stream>>>(rowptr, esorted, u, dis, b2, h3);

    // JK concat + final linear (fused)
    k_linfused<<<NTILES, 256, 0, stream>>>(x, h1, h2, h3, Wl, bl, out);
}

// Round 11
// 489.814 us; speedup vs baseline: 2.5421x; 1.2128x over previous
//
#include <hip/hip_runtime.h>
#include <hip/hip_fp16.h>

// GCN 3-layer + JK-concat.  N=100000, E=1600000, F_IN=128, H=64, F_OUT=64.
//
// R10: (1) u stored fp16 -> gather row 256B->128B, halves the dominant
// L2-fill traffic (R10 counters: gather 71us x3, FETCH=192MB, 2.7TB/s
// effective = random-line BW bound; accumulation stays fp32, h1-3 stay fp32).
// (2) count-histogram chain (6 kernels, 1.6M random global atomics) deleted:
// k_local_place2 derives counts/rowptr/dis per bucket from pairs in LDS.
// (3) dense kernels prefetch next LDS chunk into regs before FMA block;
// gather unrolled x8.
//
// Algebra: h_next[d] = relu( dis[d] * ( u[d] + sum_{s->d} u[s] ) + b ),
//          u = (h @ W) * dis[row],  dis = rsqrt(1 + indeg)

#define N_NODES 100000
#define N_EDGES 1600000
#define F_IN    128
#define HID     64
#define NBUCK   782         // ceil(N_NODES / 128)
#define NPART   128         // partition blocks
#define EPB     12500       // edges per partition block (128*12500 = 1.6M exact)
#define NTILES  1563        // ceil(N_NODES / 64)

__global__ void k_zero(int* __restrict__ p, int n) {
    int i = blockIdx.x * blockDim.x + threadIdx.x;
    if (i < n) p[i] = 0;
}

// ---- bucket partition + CSR build ----
__global__ __launch_bounds__(256) void k_bucket_hist(const int* __restrict__ dst,
                                                     int* __restrict__ bhist) {
    __shared__ int hist[NBUCK];
    for (int i = threadIdx.x; i < NBUCK; i += blockDim.x) hist[i] = 0;
    __syncthreads();
    const int e0 = blockIdx.x * EPB;
    for (int e = e0 + threadIdx.x; e < e0 + EPB; e += blockDim.x)
        atomicAdd(&hist[dst[e] >> 7], 1);
    __syncthreads();
    for (int i = threadIdx.x; i < NBUCK; i += blockDim.x)
        if (hist[i]) atomicAdd(&bhist[i], hist[i]);
}

__global__ void k_bucket_scan(int* __restrict__ bhist, int* __restrict__ bcursor,
                              int* __restrict__ rowptr) {
    __shared__ int s[1024];      // 1 block, 1024 threads
    int t = threadIdx.x;
    s[t] = (t < NBUCK) ? bhist[t] : 0;
    __syncthreads();
    for (int off = 1; off < 1024; off <<= 1) {
        int v = (t >= off) ? s[t - off] : 0;
        __syncthreads();
        s[t] += v;
        __syncthreads();
    }
    if (t < NBUCK) {
        int excl = (t == 0) ? 0 : s[t - 1];
        bhist[t] = excl;          // bucket start
        bcursor[t] = excl;        // running cursor for partition claims
    }
    if (t == NBUCK - 1) bhist[NBUCK] = s[t];   // = N_EDGES
    if (t == 0) rowptr[N_NODES] = N_EDGES;
}

__global__ __launch_bounds__(256) void k_partition(
        const int* __restrict__ src, const int* __restrict__ dst,
        int* __restrict__ bcursor, int2* __restrict__ pairs) {
    __shared__ int hist[NBUCK];
    __shared__ int cur[NBUCK];
    for (int i = threadIdx.x; i < NBUCK; i += blockDim.x) hist[i] = 0;
    __syncthreads();
    const int e0 = blockIdx.x * EPB;
    for (int e = e0 + threadIdx.x; e < e0 + EPB; e += blockDim.x)
        atomicAdd(&hist[dst[e] >> 7], 1);
    __syncthreads();
    for (int i = threadIdx.x; i < NBUCK; i += blockDim.x) {
        int c = hist[i];
        cur[i] = c ? atomicAdd(&bcursor[i], c) : 0;   // claim contiguous range
    }
    __syncthreads();
    for (int e = e0 + threadIdx.x; e < e0 + EPB; e += blockDim.x) {
        int d = dst[e];
        int pos = atomicAdd(&cur[d >> 7], 1);
        pairs[pos] = make_int2(src[e], d);
    }
}

// One block per bucket: LDS-count the bucket's pairs -> local scan -> write
// rowptr + dis, then place esorted with LDS cursors. Replaces the whole
// global count-histogram chain.
__global__ __launch_bounds__(256) void k_local_place2(
        const int2* __restrict__ pairs, const int* __restrict__ bstart,
        int* __restrict__ rowptr, float* __restrict__ dis,
        int* __restrict__ esorted) {
    __shared__ int cnt[128];
    __shared__ int scn[128];
    __shared__ int cur[128];
    const int b = blockIdx.x, nbase = b << 7, t = threadIdx.x;
    if (t < 128) cnt[t] = 0;
    __syncthreads();
    const int e0 = bstart[b], e1 = bstart[b + 1];
    for (int e = e0 + t; e < e1; e += blockDim.x)
        atomicAdd(&cnt[pairs[e].y - nbase], 1);
    __syncthreads();
    if (t < 128) scn[t] = cnt[t];
    __syncthreads();
    for (int off = 1; off < 128; off <<= 1) {
        int v = (t < 128 && t >= off) ? scn[t - off] : 0;
        __syncthreads();
        if (t < 128) scn[t] += v;
        __syncthreads();
    }
    if (t < 128) {
        int node = nbase + t;
        if (node < N_NODES) {
            int rp = e0 + scn[t] - cnt[t];       // exclusive scan + bucket base
            rowptr[node] = rp;
            cur[t] = rp;
            dis[node] = rsqrtf(1.0f + (float)cnt[t]);
        }
    }
    __syncthreads();
    for (int e = e0 + t; e < e1; e += blockDim.x) {
        int2 p = pairs[e];
        int pos = atomicAdd(&cur[p.y - nbase], 1);
        esorted[pos] = p.x;
    }
}

// ================= dense: LDS-staged 64-row tile, wave = 16-col slice =================
// Stage Xseg[64][32-chunk] coalesced; prefetch next chunk into regs before the
// FMA block so global latency hides under compute. W on the scalar path.
template<int K>
__device__ __forceinline__ void seg_staged(
        const float* __restrict__ Xseg, const float* __restrict__ Wseg,
        float* __restrict__ xs /*[64*33]*/, int r0, int lane, int jbase,
        float (&acc)[16]) {
    const int f0 = threadIdx.x,       row0 = f0 >> 3, c40 = f0 & 7;
    const int f1 = threadIdx.x + 256, row1 = f1 >> 3, c41 = f1 & 7;
    int gr0 = r0 + row0; if (gr0 >= N_NODES) gr0 = N_NODES - 1;
    int gr1 = r0 + row1; if (gr1 >= N_NODES) gr1 = N_NODES - 1;
    const float* p0 = Xseg + (size_t)gr0 * K + c40 * 4;
    const float* p1 = Xseg + (size_t)gr1 * K + c41 * 4;
    float4 v0 = *reinterpret_cast<const float4*>(p0);
    float4 v1 = *reinterpret_cast<const float4*>(p1);
    for (int kc = 0; kc < K; kc += 32) {
        float* d0 = xs + row0 * 33 + c40 * 4;
        d0[0] = v0.x; d0[1] = v0.y; d0[2] = v0.z; d0[3] = v0.w;
        float* d1 = xs + row1 * 33 + c41 * 4;
        d1[0] = v1.x; d1[1] = v1.y; d1[2] = v1.z; d1[3] = v1.w;
        __syncthreads();
        if (kc + 32 < K) {                  // prefetch next chunk during compute
            v0 = *reinterpret_cast<const float4*>(p0 + kc + 32);
            v1 = *reinterpret_cast<const float4*>(p1 + kc + 32);
        }
        const float* xrow = xs + lane * 33;
        #pragma unroll 8
        for (int kk = 0; kk < 32; ++kk) {
            float xv = xrow[kk];
            const float* wk = Wseg + (size_t)(kc + kk) * 64 + jbase;  // uniform -> s_load
            #pragma unroll
            for (int j = 0; j < 16; ++j) acc[j] = fmaf(xv, wk[j], acc[j]);
        }
        __syncthreads();
    }
}

// u_h[r][jbase:+16] = half( (X[r][:] @ W[:,slice]) * dis[r] )
template<int K>
__global__ __launch_bounds__(256, 6) void k_rowgemm(
        const float* __restrict__ X, const float* __restrict__ W,
        const float* __restrict__ dis, __half* __restrict__ u) {
    __shared__ float xs[64 * 33];       // 8448 B
    const int lane  = threadIdx.x & 63;
    const int jbase = __builtin_amdgcn_readfirstlane((threadIdx.x >> 6) * 16);
    const int r0    = blockIdx.x * 64;
    float acc[16];
    #pragma unroll
    for (int j = 0; j < 16; ++j) acc[j] = 0.f;
    seg_staged<K>(X, W, xs, r0, lane, jbase, acc);
    int r = r0 + lane;
    if (r < N_NODES) {
        float dv = dis[r];
        __half2 hv[8];
        #pragma unroll
        for (int j2 = 0; j2 < 8; ++j2)
            hv[j2] = __floats2half2_rn(acc[2*j2] * dv, acc[2*j2+1] * dv);
        float4* o = reinterpret_cast<float4*>(u + (size_t)r * 64 + jbase);  // 32B, aligned
        o[0] = *reinterpret_cast<float4*>(&hv[0]);
        o[1] = *reinterpret_cast<float4*>(&hv[4]);
    }
}

// out[r][16-slice] = bl + x@Wl[0:128] + h1@Wl[128:192] + h2@Wl[192:256] + h3@Wl[256:320]
__global__ __launch_bounds__(256, 6) void k_linfused(
        const float* __restrict__ x,  const float* __restrict__ h1,
        const float* __restrict__ h2, const float* __restrict__ h3,
        const float* __restrict__ Wl, const float* __restrict__ bl,
        float* __restrict__ out) {
    __shared__ float xs[64 * 33];
    const int lane  = threadIdx.x & 63;
    const int jbase = __builtin_amdgcn_readfirstlane((threadIdx.x >> 6) * 16);
    const int r0    = blockIdx.x * 64;
    float acc[16];
    const float* blh = bl + jbase;
    #pragma unroll
    for (int j = 0; j < 16; ++j) acc[j] = blh[j];        // uniform -> s_load
    seg_staged<F_IN>(x,  Wl,            xs, r0, lane, jbase, acc);
    seg_staged<HID >(h1, Wl + 128 * 64, xs, r0, lane, jbase, acc);
    seg_staged<HID >(h2, Wl + 192 * 64, xs, r0, lane, jbase, acc);
    seg_staged<HID >(h3, Wl + 256 * 64, xs, r0, lane, jbase, acc);
    int r = r0 + lane;
    if (r < N_NODES) {
        float* orow = out + (size_t)r * 64 + jbase;
        #pragma unroll
        for (int j4 = 0; j4 < 4; ++j4) {
            float4 st = { acc[4*j4], acc[4*j4+1], acc[4*j4+2], acc[4*j4+3] };
            *reinterpret_cast<float4*>(orow + 4 * j4) = st;
        }
    }
}

// ================= gather: h = relu(dis[d]*(u[d]+sum u[s]) + b), u is fp16 =================
__global__ __launch_bounds__(256) void k_gather_relu(
        const int* __restrict__ rowptr, const int* __restrict__ es,
        const __half* __restrict__ u, const float* __restrict__ dis,
        const float* __restrict__ bias, float* __restrict__ hout) {
    const int lane = threadIdx.x & 63, wid = threadIdx.x >> 6, wpb = blockDim.x >> 6;
    const float bj = bias[lane];
    for (int d = blockIdx.x * wpb + wid; d < N_NODES; d += gridDim.x * wpb) {
        float a = __half2float(u[(size_t)d * 64 + lane]);     // self loop
        int i = rowptr[d], end = rowptr[d + 1];
        for (; i + 8 <= end; i += 8) {
            int s0 = es[i],     s1 = es[i + 1], s2 = es[i + 2], s3 = es[i + 3];
            int s4 = es[i + 4], s5 = es[i + 5], s6 = es[i + 6], s7 = es[i + 7];
            float v0 = __half2float(u[(size_t)s0 * 64 + lane]);
            float v1 = __half2float(u[(size_t)s1 * 64 + lane]);
            float v2 = __half2float(u[(size_t)s2 * 64 + lane]);
            float v3 = __half2float(u[(size_t)s3 * 64 + lane]);
            float v4 = __half2float(u[(size_t)s4 * 64 + lane]);
            float v5 = __half2float(u[(size_t)s5 * 64 + lane]);
            float v6 = __half2float(u[(size_t)s6 * 64 + lane]);
            float v7 = __half2float(u[(size_t)s7 * 64 + lane]);
            a += v0; a += v1; a += v2; a += v3;
            a += v4; a += v5; a += v6; a += v7;
        }
        for (; i < end; i++) a += __half2float(u[(size_t)es[i] * 64 + lane]);
        float v = fmaf(a, dis[d], bj);
        hout[(size_t)d * HID + lane] = v > 0.f ? v : 0.f;
    }
}

// ================= launch =================
extern "C" void kernel_launch(void* const* d_in, const int* in_sizes, int n_in,
                              void* d_out, int out_size, void* d_ws, size_t ws_size,
                              hipStream_t stream) {
    const float* x  = (const float*)d_in[0];
    const int*   ei = (const int*)d_in[1];      // edge_index [2, E] int32
    const float* W0 = (const float*)d_in[2];
    const float* b0 = (const float*)d_in[3];
    const float* W1 = (const float*)d_in[4];
    const float* b1 = (const float*)d_in[5];
    const float* W2 = (const float*)d_in[6];
    const float* b2 = (const float*)d_in[7];
    const float* Wl = (const float*)d_in[8];
    const float* bl = (const float*)d_in[9];
    float* out = (float*)d_out;

    const int* esrc = ei;
    const int* edst = ei + N_EDGES;

    // workspace layout (byte offsets; high-water unchanged ~110.5 MB)
    char* w = (char*)d_ws;
    float* dis     = (float*)(w);                       //   409,600 B
    __half* u      = (__half*)(w + 409600);             // 12,800,000 (fp16 now)
    float* h1      = (float*)(w + 26009600);            // 25,600,000
    float* h2      = (float*)(w + 51609600);            // 25,600,000
    float* h3      = (float*)(w + 77209600);            // 25,600,000
    int*   rowptr  = (int*)  (w + 103219200);           //    409,600 (N+1)
    int*   bhist   = (int*)  (w + 103628800);           //      4,096 (NBUCK+1)
    int*   bcursor = (int*)  (w + 103632896);           //      4,096
    int*   esorted = (int*)  (w + 104038400);           //  6,400,000
    int2*  pairs   = (int2*) (w + 409600);              // aliases u (build-only)

    // CSR build via bucket partition (ws re-poisoned each call)
    k_zero<<<4, 256, 0, stream>>>(bhist, 1024);
    k_bucket_hist<<<NPART, 256, 0, stream>>>(edst, bhist);
    k_bucket_scan<<<1, 1024, 0, stream>>>(bhist, bcursor, rowptr);
    k_partition<<<NPART, 256, 0, stream>>>(esrc, edst, bcursor, pairs);
    k_local_place2<<<NBUCK, 256, 0, stream>>>(pairs, bhist, rowptr, dis, esorted);

    // layer 0
    k_rowgemm<F_IN><<<NTILES, 256, 0, stream>>>(x, W0, dis, u);
    k_gather_relu<<<2048, 256, 0, stream>>>(rowptr, esorted, u, dis, b0, h1);
    // layer 1
    k_rowgemm<HID><<<NTILES, 256, 0, stream>>>(h1, W1, dis, u);
    k_gather_relu<<<2048, 256, 0, stream>>>(rowptr, esorted, u, dis, b1, h2);
    // layer 2
    k_rowgemm<HID><<<NTILES, 256, 0, stream>>>(h2, W2, dis, u);
    k_gather_relu<<<2048, 256, 0, stream>>>(rowptr, esorted, u, dis, b2, h3);

    // JK concat + final linear (fused)
    k_linfused<<<NTILES, 256, 0, stream>>>(x, h1, h2, h3, Wl, bl, out);
}